// Round 1
// baseline (398.346 us; speedup 1.0000x reference)
//
#include <hip/hip_runtime.h>

#define BB 2048
#define K 32
#define ROW 2056   // L1 + P
#define L1D 2048

__device__ __forceinline__ void fma4(float4& a, float v, const float4 t) {
    a.x = fmaf(v, t.x, a.x); a.y = fmaf(v, t.y, a.y);
    a.z = fmaf(v, t.z, a.z); a.w = fmaf(v, t.w, a.w);
}

__device__ __forceinline__ float4 add4(float4 a, float4 b) {
    float4 r; r.x = a.x + b.x; r.y = a.y + b.y; r.z = a.z + b.z; r.w = a.w + b.w;
    return r;
}

__device__ __forceinline__ float4 mix4(float ua, float4 a, float ub, float4 b) {
    float4 r;
    r.x = ua * a.x + ub * b.x; r.y = ua * a.y + ub * b.y;
    r.z = ua * a.z + ub * b.z; r.w = ua * a.w + ub * b.w;
    return r;
}

__device__ __forceinline__ float lsq1(float g, float s) {
    return rintf(fminf(fmaxf(g / s, 0.f), 255.f)) * s;
}

__device__ __forceinline__ float4 lsq4(float4 g, float s) {
    float4 r;
    r.x = lsq1(g.x, s); r.y = lsq1(g.y, s); r.z = lsq1(g.z, s); r.w = lsq1(g.w, s);
    return r;
}

__global__ __launch_bounds__(256) void nnue_fwd(
    const float* __restrict__ us_p,
    const float* __restrict__ them_p,
    const int*   __restrict__ widx,
    const float* __restrict__ wval,
    const int*   __restrict__ bidx,
    const float* __restrict__ bval,
    const int*   __restrict__ psqt_idx,
    const int*   __restrict__ ls_idx,
    const float* __restrict__ ftw,
    const float* __restrict__ ftb,
    const float* __restrict__ lsq_s,
    const float* __restrict__ W1,
    const float* __restrict__ b1,
    const float* __restrict__ W2,
    const float* __restrict__ b2,
    const float* __restrict__ Wo,
    const float* __restrict__ bo,
    float* __restrict__ out)
{
    const int b    = blockIdx.x;
    const int tid  = threadIdx.x;
    const int lane = tid & 63;
    const int wave = tid >> 6;

    __shared__ int   sWI[K], sBI[K];
    __shared__ float sWV[K], sBV[K];
    __shared__ float sM[L1D];       // l0_mixed
    __shared__ float sPs[16];       // wpsqt[0..7], bpsqt[8..15]
    __shared__ float sRed[4][16];
    __shared__ float sH1[16];
    __shared__ float sH2[32];

    if (tid < K) {
        sWI[tid] = widx[b * K + tid];
        sWV[tid] = wval[b * K + tid];
        sBI[tid] = bidx[b * K + tid];
        sBV[tid] = bval[b * K + tid];
    }
    __syncthreads();

    const float usv = us_p[b];
    const float thv = them_p[b];

    // ---- feature transform: register accumulation of 2 float4 col-groups/side ----
    float4 aw0 = {0,0,0,0}, aw1 = {0,0,0,0};
    float4 ab0 = {0,0,0,0}, ab1 = {0,0,0,0};

    #pragma unroll 4
    for (int k = 0; k < K; ++k) {
        const float4* rw = (const float4*)(ftw + (size_t)sWI[k] * ROW);
        const float4* rb = (const float4*)(ftw + (size_t)sBI[k] * ROW);
        const float vw = sWV[k];
        const float vb = sBV[k];
        fma4(aw0, vw, rw[tid]);
        fma4(aw1, vw, rw[tid + 256]);
        fma4(ab0, vb, rb[tid]);
        fma4(ab1, vb, rb[tid + 256]);
    }

    // psqt columns 2048..2055 (float4 groups 512,513) by 4 threads
    if (tid < 4) {
        const int side = tid >> 1;             // 0 = white, 1 = black
        const int d4   = 512 + (tid & 1);
        const int*   idx = side ? sBI : sWI;
        const float* val = side ? sBV : sWV;
        float4 acc = {0,0,0,0};
        for (int k = 0; k < K; ++k) {
            const float4* r = (const float4*)(ftw + (size_t)idx[k] * ROW);
            fma4(acc, val[k], r[d4]);
        }
        acc = add4(acc, ((const float4*)ftb)[d4]);
        ((float4*)sPs)[tid] = acc;             // [w0 w1 b0 b1]
    }

    // bias
    const float4 bl = ((const float4*)ftb)[tid];
    const float4 bh = ((const float4*)ftb)[tid + 256];
    aw0 = add4(aw0, bl); aw1 = add4(aw1, bh);
    ab0 = add4(ab0, bl); ab1 = add4(ab1, bh);

    // ---- perspective mix + LSQ quantize + pairwise multiply ----
    const float s0 = lsq_s[0], s1 = lsq_s[1], s2 = lsq_s[2], s3 = lsq_s[3];
    const float4 q0 = lsq4(mix4(usv, aw0, thv, ab0), s0);   // l0[0:1024)
    const float4 q1 = lsq4(mix4(usv, aw1, thv, ab1), s1);   // l0[1024:2048)
    const float4 q2 = lsq4(mix4(usv, ab0, thv, aw0), s2);   // l0[2048:3072)
    const float4 q3 = lsq4(mix4(usv, ab1, thv, aw1), s3);   // l0[3072:4096)

    float4 mlo, mhi;
    mlo.x = q0.x * q1.x; mlo.y = q0.y * q1.y; mlo.z = q0.z * q1.z; mlo.w = q0.w * q1.w;
    mhi.x = q2.x * q3.x; mhi.y = q2.y * q3.y; mhi.z = q2.z * q3.z; mhi.w = q2.w * q3.w;

    ((float4*)sM)[tid]       = mlo;
    ((float4*)sM)[tid + 256] = mhi;
    __syncthreads();

    // ---- layer stack: h1 = clip(W1[i] @ mixed + b1[i], 0, 1) ----
    const int i = ls_idx[b];
    const float* W1i = W1 + (size_t)i * 16 * L1D;

    float acc[16];
    #pragma unroll
    for (int o = 0; o < 16; ++o) acc[o] = 0.f;

    #pragma unroll
    for (int jj = 0; jj < 8; ++jj) {
        const int j = tid + 256 * jj;
        const float m = sM[j];
        #pragma unroll
        for (int o = 0; o < 16; ++o)
            acc[o] = fmaf(m, W1i[o * L1D + j], acc[o]);
    }

    #pragma unroll
    for (int o = 0; o < 16; ++o) {
        float v = acc[o];
        v += __shfl_down(v, 32); v += __shfl_down(v, 16); v += __shfl_down(v, 8);
        v += __shfl_down(v, 4);  v += __shfl_down(v, 2);  v += __shfl_down(v, 1);
        if (lane == 0) sRed[wave][o] = v;
    }
    __syncthreads();

    if (tid < 16) {
        float v = sRed[0][tid] + sRed[1][tid] + sRed[2][tid] + sRed[3][tid];
        v += b1[i * 16 + tid];
        sH1[tid] = fminf(fmaxf(v, 0.f), 1.f);
    }
    __syncthreads();

    if (tid < 32) {
        const float* W2i = W2 + (size_t)i * 32 * 16 + tid * 16;
        float v = b2[i * 32 + tid];
        #pragma unroll
        for (int j = 0; j < 16; ++j) v = fmaf(sH1[j], W2i[j], v);
        sH2[tid] = fminf(fmaxf(v, 0.f), 1.f);
    }
    __syncthreads();

    if (tid == 0) {
        const float* Woi = Wo + (size_t)i * 32;
        float v = bo[i];
        #pragma unroll
        for (int j = 0; j < 32; ++j) v = fmaf(sH2[j], Woi[j], v);
        const int pi = psqt_idx[b];
        const float wps = sPs[pi];
        const float bps = sPs[8 + pi];
        out[b] = v + (wps - bps) * (usv - 0.5f);
    }
}

extern "C" void kernel_launch(void* const* d_in, const int* in_sizes, int n_in,
                              void* d_out, int out_size, void* d_ws, size_t ws_size,
                              hipStream_t stream) {
    const float* us_p  = (const float*)d_in[0];
    const float* them  = (const float*)d_in[1];
    const int*   widx  = (const int*)d_in[2];
    const float* wval  = (const float*)d_in[3];
    const int*   bidx  = (const int*)d_in[4];
    const float* bval  = (const float*)d_in[5];
    const int*   pidx  = (const int*)d_in[6];
    const int*   lidx  = (const int*)d_in[7];
    const float* ftw   = (const float*)d_in[8];
    const float* ftb   = (const float*)d_in[9];
    const float* lsqs  = (const float*)d_in[10];
    const float* W1    = (const float*)d_in[11];
    const float* b1    = (const float*)d_in[12];
    const float* W2    = (const float*)d_in[13];
    const float* b2    = (const float*)d_in[14];
    const float* Wo    = (const float*)d_in[15];
    const float* bo    = (const float*)d_in[16];
    float* out = (float*)d_out;

    nnue_fwd<<<dim3(BB), dim3(256), 0, stream>>>(
        us_p, them, widx, wval, bidx, bval, pidx, lidx,
        ftw, ftb, lsqs, W1, b1, W2, b2, Wo, bo, out);
}

// Round 2
// 396.476 us; speedup vs baseline: 1.0047x; 1.0047x over previous
//
#include <hip/hip_runtime.h>

#define BB 2048
#define K 32
#define ROW 2056   // L1 + P (floats per ft_weight row); 8224 B, 16B-aligned
#define L1D 2048
#define NT 512

__device__ __forceinline__ void fma4(float4& a, float v, const float4 t) {
    a.x = fmaf(v, t.x, a.x); a.y = fmaf(v, t.y, a.y);
    a.z = fmaf(v, t.z, a.z); a.w = fmaf(v, t.w, a.w);
}

__device__ __forceinline__ float4 add4(float4 a, float4 b) {
    float4 r; r.x = a.x + b.x; r.y = a.y + b.y; r.z = a.z + b.z; r.w = a.w + b.w;
    return r;
}

__device__ __forceinline__ float4 mix4(float ua, float4 a, float ub, float4 b) {
    float4 r;
    r.x = fmaf(ua, a.x, ub * b.x); r.y = fmaf(ua, a.y, ub * b.y);
    r.z = fmaf(ua, a.z, ub * b.z); r.w = fmaf(ua, a.w, ub * b.w);
    return r;
}

__device__ __forceinline__ float lsq1(float g, float s) {
    return rintf(fminf(fmaxf(g / s, 0.f), 255.f)) * s;
}

__device__ __forceinline__ float4 lsq4(float4 g, float s) {
    float4 r;
    r.x = lsq1(g.x, s); r.y = lsq1(g.y, s); r.z = lsq1(g.z, s); r.w = lsq1(g.w, s);
    return r;
}

__device__ __forceinline__ float4 mul4(float4 a, float4 b) {
    float4 r; r.x = a.x * b.x; r.y = a.y * b.y; r.z = a.z * b.z; r.w = a.w * b.w;
    return r;
}

__global__ __launch_bounds__(NT, 8) void nnue_fwd(
    const float* __restrict__ us_p,
    const float* __restrict__ them_p,
    const int*   __restrict__ widx,
    const float* __restrict__ wval,
    const int*   __restrict__ bidx,
    const float* __restrict__ bval,
    const int*   __restrict__ psqt_idx,
    const int*   __restrict__ ls_idx,
    const float* __restrict__ ftw,
    const float* __restrict__ ftb,
    const float* __restrict__ lsq_s,
    const float* __restrict__ W1,
    const float* __restrict__ b1,
    const float* __restrict__ W2,
    const float* __restrict__ b2,
    const float* __restrict__ Wo,
    const float* __restrict__ bo,
    float* __restrict__ out)
{
    const int b = blockIdx.x;
    const int t = threadIdx.x;

    __shared__ float4 sQA[NT];      // quantized l0[0:2048)
    __shared__ float4 sQB[NT];      // quantized l0[2048:4096)
    __shared__ float4 sM[NT];       // l0_mixed (2048 floats)
    __shared__ float  sH1t[16];     // pre-bias W1 output
    __shared__ float  sH1[16];
    __shared__ float  sH2[32];
    __shared__ float  sPsq;

    const float usv = us_p[b];
    const float thv = them_p[b];

    // ---- phase 1: feature-transform gather; 1 float4 group/side/thread ----
    // row index & value are wave-uniform -> scalar loads, saddr-form vmem.
    float4 aw = {0,0,0,0}, ab = {0,0,0,0};
    #pragma unroll 4
    for (int k = 0; k < K; ++k) {
        const int   iw = widx[b * K + k];
        const float vw = wval[b * K + k];
        const int   ib = bidx[b * K + k];
        const float vb = bval[b * K + k];
        const float4* rw = (const float4*)(ftw + (size_t)iw * ROW);
        const float4* rb = (const float4*)(ftw + (size_t)ib * ROW);
        fma4(aw, vw, rw[t]);
        fma4(ab, vb, rb[t]);
    }

    // ---- phase 2: PSQT — only the selected column matters ----
    const int pi = psqt_idx[b];
    if (t < 64) {
        const int k = t & 31;
        const int   idx = (t < 32) ? widx[b * K + k] : bidx[b * K + k];
        const float val = (t < 32) ? wval[b * K + k] : bval[b * K + k];
        float c = val * ftw[(size_t)idx * ROW + 2048 + pi];
        c += __shfl_down(c, 16, 32); c += __shfl_down(c, 8, 32);
        c += __shfl_down(c, 4, 32);  c += __shfl_down(c, 2, 32);
        c += __shfl_down(c, 1, 32);
        const float bsum = __shfl(c, 32);    // lane32's reduced black sum
        if (t == 0) sPsq = (c - bsum) * (usv - 0.5f);   // ft_bias cancels in (wps-bps)
    }

    // ---- phase 3: bias + perspective mix + LSQ quantize ----
    const float s0 = lsq_s[0], s1 = lsq_s[1], s2 = lsq_s[2], s3 = lsq_s[3];
    const float4 bias = ((const float4*)ftb)[t];
    aw = add4(aw, bias);
    ab = add4(ab, bias);
    const float sA = (t < 256) ? s0 : s1;
    const float sB = (t < 256) ? s2 : s3;
    sQA[t] = lsq4(mix4(usv, aw, thv, ab), sA);
    sQB[t] = lsq4(mix4(usv, ab, thv, aw), sB);
    __syncthreads();

    // ---- phase 4: pairwise multiply -> l0_mixed ----
    if (t < 256) {
        sM[t]       = mul4(sQA[t], sQA[t + 256]);
        sM[t + 256] = mul4(sQB[t], sQB[t + 256]);
    }
    __syncthreads();

    // ---- phase 5: h1 = clip(W1[i] @ mixed + b1[i]) ; 32 threads/output ----
    const int i = ls_idx[b];
    const float* W1i = W1 + (size_t)i * 16 * L1D;
    {
        const int o   = t >> 5;
        const int sub = t & 31;
        const float4* Wrow = (const float4*)(W1i + o * L1D);
        float4 a4 = {0,0,0,0};
        #pragma unroll
        for (int jj = 0; jj < 16; ++jj) {
            const int j4 = sub + (jj << 5);
            const float4 m = sM[j4];
            const float4 w = Wrow[j4];
            a4.x = fmaf(m.x, w.x, a4.x); a4.y = fmaf(m.y, w.y, a4.y);
            a4.z = fmaf(m.z, w.z, a4.z); a4.w = fmaf(m.w, w.w, a4.w);
        }
        float acc = (a4.x + a4.y) + (a4.z + a4.w);
        acc += __shfl_down(acc, 16, 32); acc += __shfl_down(acc, 8, 32);
        acc += __shfl_down(acc, 4, 32);  acc += __shfl_down(acc, 2, 32);
        acc += __shfl_down(acc, 1, 32);
        if (sub == 0) sH1t[o] = acc;
    }
    __syncthreads();

    if (t < 16) {
        const float v = sH1t[t] + b1[i * 16 + t];
        sH1[t] = fminf(fmaxf(v, 0.f), 1.f);
    }
    __syncthreads();

    // ---- phase 6: h2, output ----
    if (t < 32) {
        const float* W2i = W2 + (size_t)i * 32 * 16 + t * 16;
        float v = b2[i * 32 + t];
        #pragma unroll
        for (int j = 0; j < 16; ++j) v = fmaf(sH1[j], W2i[j], v);
        sH2[t] = fminf(fmaxf(v, 0.f), 1.f);
    }
    __syncthreads();

    if (t == 0) {
        const float* Woi = Wo + (size_t)i * 32;
        float v = bo[i];
        #pragma unroll
        for (int j = 0; j < 32; ++j) v = fmaf(sH2[j], Woi[j], v);
        out[b] = v + sPsq;
    }
}

extern "C" void kernel_launch(void* const* d_in, const int* in_sizes, int n_in,
                              void* d_out, int out_size, void* d_ws, size_t ws_size,
                              hipStream_t stream) {
    const float* us_p  = (const float*)d_in[0];
    const float* them  = (const float*)d_in[1];
    const int*   widx  = (const int*)d_in[2];
    const float* wval  = (const float*)d_in[3];
    const int*   bidx  = (const int*)d_in[4];
    const float* bval  = (const float*)d_in[5];
    const int*   pidx  = (const int*)d_in[6];
    const int*   lidx  = (const int*)d_in[7];
    const float* ftw   = (const float*)d_in[8];
    const float* ftb   = (const float*)d_in[9];
    const float* lsqs  = (const float*)d_in[10];
    const float* W1    = (const float*)d_in[11];
    const float* b1    = (const float*)d_in[12];
    const float* W2    = (const float*)d_in[13];
    const float* b2    = (const float*)d_in[14];
    const float* Wo    = (const float*)d_in[15];
    const float* bo    = (const float*)d_in[16];
    float* out = (float*)d_out;

    nnue_fwd<<<dim3(BB), dim3(NT), 0, stream>>>(
        us_p, them, widx, wval, bidx, bval, pidx, lidx,
        ftw, ftb, lsqs, W1, b1, W2, b2, Wo, bo, out);
}

// Round 3
// 371.484 us; speedup vs baseline: 1.0723x; 1.0673x over previous
//
#include <hip/hip_runtime.h>

#define BB 2048
#define K 32
#define ROW 2056          // L1 + P floats per ft_weight row
#define L1D 2048
#define NT 512
#define NFEAT 22528
#define TBL_ELEMS ((size_t)NFEAT * ROW)        // 46,317,568
#define W1_ELEMS  ((size_t)8 * 16 * L1D)       // 262,144
#define TBL_BYTES (TBL_ELEMS * 2)              // 92,635,136
#define W1_OFF    TBL_BYTES                    // 16B aligned
#define WS_NEEDED (TBL_BYTES + W1_ELEMS * 2)

__device__ __forceinline__ float bf2f(unsigned short s) {
    union { unsigned int u; float f; } v; v.u = ((unsigned int)s) << 16; return v.f;
}

__device__ __forceinline__ unsigned short f2bf(float f) {
    union { float f; unsigned int u; } v; v.f = f;
    const unsigned int u = v.u;
    return (unsigned short)((u + 0x7fffu + ((u >> 16) & 1u)) >> 16);  // RNE; inputs finite
}

__device__ __forceinline__ void fma4(float4& a, float v, const float4 t) {
    a.x = fmaf(v, t.x, a.x); a.y = fmaf(v, t.y, a.y);
    a.z = fmaf(v, t.z, a.z); a.w = fmaf(v, t.w, a.w);
}

__device__ __forceinline__ void fma4u(float4& a, float v, const ushort4 t) {
    a.x = fmaf(v, bf2f(t.x), a.x); a.y = fmaf(v, bf2f(t.y), a.y);
    a.z = fmaf(v, bf2f(t.z), a.z); a.w = fmaf(v, bf2f(t.w), a.w);
}

__device__ __forceinline__ float4 add4(float4 a, float4 b) {
    float4 r; r.x = a.x + b.x; r.y = a.y + b.y; r.z = a.z + b.z; r.w = a.w + b.w;
    return r;
}

__device__ __forceinline__ float4 mix4(float ua, float4 a, float ub, float4 b) {
    float4 r;
    r.x = fmaf(ua, a.x, ub * b.x); r.y = fmaf(ua, a.y, ub * b.y);
    r.z = fmaf(ua, a.z, ub * b.z); r.w = fmaf(ua, a.w, ub * b.w);
    return r;
}

__device__ __forceinline__ float lsq1(float g, float s) {
    return rintf(fminf(fmaxf(g / s, 0.f), 255.f)) * s;
}

__device__ __forceinline__ float4 lsq4(float4 g, float s) {
    float4 r;
    r.x = lsq1(g.x, s); r.y = lsq1(g.y, s); r.z = lsq1(g.z, s); r.w = lsq1(g.w, s);
    return r;
}

__device__ __forceinline__ float4 mul4(float4 a, float4 b) {
    float4 r; r.x = a.x * b.x; r.y = a.y * b.y; r.z = a.z * b.z; r.w = a.w * b.w;
    return r;
}

// ---- streaming fp32 -> bf16 conversion (grid-stride over float4 groups) ----
__global__ __launch_bounds__(256) void conv_bf16(const float* __restrict__ src,
                                                 unsigned short* __restrict__ dst,
                                                 int n4) {
    int i = blockIdx.x * 256 + threadIdx.x;
    const int stride = gridDim.x * 256;
    for (; i < n4; i += stride) {
        const float4 v = ((const float4*)src)[i];
        ushort4 o;
        o.x = f2bf(v.x); o.y = f2bf(v.y); o.z = f2bf(v.z); o.w = f2bf(v.w);
        ((ushort4*)dst)[i] = o;
    }
}

// ---- main fused kernel, bf16 table + bf16 W1 ----
__global__ __launch_bounds__(NT, 8) void nnue_fwd_bf16(
    const float* __restrict__ us_p,
    const float* __restrict__ them_p,
    const int*   __restrict__ widx,
    const float* __restrict__ wval,
    const int*   __restrict__ bidx,
    const float* __restrict__ bval,
    const int*   __restrict__ psqt_idx,
    const int*   __restrict__ ls_idx,
    const unsigned short* __restrict__ tbl,   // bf16 ft_weight [NFEAT][ROW]
    const float* __restrict__ ftb,
    const float* __restrict__ lsq_s,
    const unsigned short* __restrict__ w1bf,  // bf16 W1 [8][16][2048]
    const float* __restrict__ b1,
    const float* __restrict__ W2,
    const float* __restrict__ b2,
    const float* __restrict__ Wo,
    const float* __restrict__ bo,
    float* __restrict__ out)
{
    const int b = blockIdx.x;
    const int t = threadIdx.x;

    __shared__ float4 sQA[NT];
    __shared__ float4 sQB[NT];
    __shared__ float4 sM[NT];
    __shared__ float  sH1t[16];
    __shared__ float  sH1[16];
    __shared__ float  sH2[32];
    __shared__ float  sPsq;

    const float usv = us_p[b];
    const float thv = them_p[b];

    // ---- phase 1: gather-accumulate, 4 bf16 cols/side/thread ----
    float4 aw = {0,0,0,0}, ab = {0,0,0,0};
    #pragma unroll 4
    for (int k = 0; k < K; ++k) {
        const int   iw = widx[b * K + k];
        const float vw = wval[b * K + k];
        const int   ib = bidx[b * K + k];
        const float vb = bval[b * K + k];
        const ushort4 uw = ((const ushort4*)(tbl + (size_t)iw * ROW))[t];
        const ushort4 ub = ((const ushort4*)(tbl + (size_t)ib * ROW))[t];
        fma4u(aw, vw, uw);
        fma4u(ab, vb, ub);
    }

    // ---- phase 2: PSQT, selected column only ----
    const int pi = psqt_idx[b];
    if (t < 64) {
        const int k = t & 31;
        const int   idx = (t < 32) ? widx[b * K + k] : bidx[b * K + k];
        const float val = (t < 32) ? wval[b * K + k] : bval[b * K + k];
        float c = val * bf2f(tbl[(size_t)idx * ROW + 2048 + pi]);
        c += __shfl_down(c, 16, 32); c += __shfl_down(c, 8, 32);
        c += __shfl_down(c, 4, 32);  c += __shfl_down(c, 2, 32);
        c += __shfl_down(c, 1, 32);
        const float bsum = __shfl(c, 32);
        if (t == 0) sPsq = (c - bsum) * (usv - 0.5f);   // ft_bias cancels in (wps - bps)
    }

    // ---- phase 3: bias + mix + LSQ ----
    const float s0 = lsq_s[0], s1 = lsq_s[1], s2 = lsq_s[2], s3 = lsq_s[3];
    const float4 bias = ((const float4*)ftb)[t];
    aw = add4(aw, bias);
    ab = add4(ab, bias);
    const float sA = (t < 256) ? s0 : s1;
    const float sB = (t < 256) ? s2 : s3;
    sQA[t] = lsq4(mix4(usv, aw, thv, ab), sA);
    sQB[t] = lsq4(mix4(usv, ab, thv, aw), sB);
    __syncthreads();

    // ---- phase 4: pairwise multiply ----
    if (t < 256) {
        sM[t]       = mul4(sQA[t], sQA[t + 256]);
        sM[t + 256] = mul4(sQB[t], sQB[t + 256]);
    }
    __syncthreads();

    // ---- phase 5: h1 = clip(W1[i] @ mixed + b1[i]); 32 threads/output ----
    const int i = ls_idx[b];
    const unsigned short* W1i = w1bf + (size_t)i * 16 * L1D;
    {
        const int o   = t >> 5;
        const int sub = t & 31;
        const ushort4* Wrow = (const ushort4*)(W1i + o * L1D);
        float4 a4 = {0,0,0,0};
        #pragma unroll
        for (int jj = 0; jj < 16; ++jj) {
            const int j4 = sub + (jj << 5);
            const float4  m = sM[j4];
            const ushort4 w = Wrow[j4];
            a4.x = fmaf(m.x, bf2f(w.x), a4.x); a4.y = fmaf(m.y, bf2f(w.y), a4.y);
            a4.z = fmaf(m.z, bf2f(w.z), a4.z); a4.w = fmaf(m.w, bf2f(w.w), a4.w);
        }
        float acc = (a4.x + a4.y) + (a4.z + a4.w);
        acc += __shfl_down(acc, 16, 32); acc += __shfl_down(acc, 8, 32);
        acc += __shfl_down(acc, 4, 32);  acc += __shfl_down(acc, 2, 32);
        acc += __shfl_down(acc, 1, 32);
        if (sub == 0) sH1t[o] = acc;
    }
    __syncthreads();

    if (t < 16) {
        const float v = sH1t[t] + b1[i * 16 + t];
        sH1[t] = fminf(fmaxf(v, 0.f), 1.f);
    }
    __syncthreads();

    if (t < 32) {
        const float* W2i = W2 + (size_t)i * 32 * 16 + t * 16;
        float v = b2[i * 32 + t];
        #pragma unroll
        for (int j = 0; j < 16; ++j) v = fmaf(sH1[j], W2i[j], v);
        sH2[t] = fminf(fmaxf(v, 0.f), 1.f);
    }
    __syncthreads();

    if (t == 0) {
        const float* Woi = Wo + (size_t)i * 32;
        float v = bo[i];
        #pragma unroll
        for (int j = 0; j < 32; ++j) v = fmaf(sH2[j], Woi[j], v);
        out[b] = v + sPsq;
    }
}

// ---- fallback: R2 fp32 kernel (used only if ws_size is too small) ----
__global__ __launch_bounds__(NT, 8) void nnue_fwd_f32(
    const float* __restrict__ us_p, const float* __restrict__ them_p,
    const int* __restrict__ widx, const float* __restrict__ wval,
    const int* __restrict__ bidx, const float* __restrict__ bval,
    const int* __restrict__ psqt_idx, const int* __restrict__ ls_idx,
    const float* __restrict__ ftw, const float* __restrict__ ftb,
    const float* __restrict__ lsq_s, const float* __restrict__ W1,
    const float* __restrict__ b1, const float* __restrict__ W2,
    const float* __restrict__ b2, const float* __restrict__ Wo,
    const float* __restrict__ bo, float* __restrict__ out)
{
    const int b = blockIdx.x;
    const int t = threadIdx.x;
    __shared__ float4 sQA[NT]; __shared__ float4 sQB[NT]; __shared__ float4 sM[NT];
    __shared__ float sH1t[16]; __shared__ float sH1[16]; __shared__ float sH2[32];
    __shared__ float sPsq;
    const float usv = us_p[b]; const float thv = them_p[b];
    float4 aw = {0,0,0,0}, ab = {0,0,0,0};
    #pragma unroll 4
    for (int k = 0; k < K; ++k) {
        const int iw = widx[b*K+k]; const float vw = wval[b*K+k];
        const int ib = bidx[b*K+k]; const float vb = bval[b*K+k];
        fma4(aw, vw, ((const float4*)(ftw + (size_t)iw * ROW))[t]);
        fma4(ab, vb, ((const float4*)(ftw + (size_t)ib * ROW))[t]);
    }
    const int pi = psqt_idx[b];
    if (t < 64) {
        const int k = t & 31;
        const int   idx = (t < 32) ? widx[b*K+k] : bidx[b*K+k];
        const float val = (t < 32) ? wval[b*K+k] : bval[b*K+k];
        float c = val * ftw[(size_t)idx * ROW + 2048 + pi];
        c += __shfl_down(c, 16, 32); c += __shfl_down(c, 8, 32);
        c += __shfl_down(c, 4, 32); c += __shfl_down(c, 2, 32); c += __shfl_down(c, 1, 32);
        const float bsum = __shfl(c, 32);
        if (t == 0) sPsq = (c - bsum) * (usv - 0.5f);
    }
    const float s0 = lsq_s[0], s1 = lsq_s[1], s2 = lsq_s[2], s3 = lsq_s[3];
    const float4 bias = ((const float4*)ftb)[t];
    aw = add4(aw, bias); ab = add4(ab, bias);
    const float sA = (t < 256) ? s0 : s1;
    const float sB = (t < 256) ? s2 : s3;
    sQA[t] = lsq4(mix4(usv, aw, thv, ab), sA);
    sQB[t] = lsq4(mix4(usv, ab, thv, aw), sB);
    __syncthreads();
    if (t < 256) { sM[t] = mul4(sQA[t], sQA[t+256]); sM[t+256] = mul4(sQB[t], sQB[t+256]); }
    __syncthreads();
    const int i = ls_idx[b];
    const float* W1i = W1 + (size_t)i * 16 * L1D;
    {
        const int o = t >> 5; const int sub = t & 31;
        const float4* Wrow = (const float4*)(W1i + o * L1D);
        float4 a4 = {0,0,0,0};
        #pragma unroll
        for (int jj = 0; jj < 16; ++jj) {
            const int j4 = sub + (jj << 5);
            const float4 m = sM[j4]; const float4 w = Wrow[j4];
            a4.x = fmaf(m.x, w.x, a4.x); a4.y = fmaf(m.y, w.y, a4.y);
            a4.z = fmaf(m.z, w.z, a4.z); a4.w = fmaf(m.w, w.w, a4.w);
        }
        float acc = (a4.x + a4.y) + (a4.z + a4.w);
        acc += __shfl_down(acc, 16, 32); acc += __shfl_down(acc, 8, 32);
        acc += __shfl_down(acc, 4, 32); acc += __shfl_down(acc, 2, 32); acc += __shfl_down(acc, 1, 32);
        if (sub == 0) sH1t[o] = acc;
    }
    __syncthreads();
    if (t < 16) sH1[t] = fminf(fmaxf(sH1t[t] + b1[i*16+t], 0.f), 1.f);
    __syncthreads();
    if (t < 32) {
        const float* W2i = W2 + (size_t)i * 32 * 16 + t * 16;
        float v = b2[i*32+t];
        #pragma unroll
        for (int j = 0; j < 16; ++j) v = fmaf(sH1[j], W2i[j], v);
        sH2[t] = fminf(fmaxf(v, 0.f), 1.f);
    }
    __syncthreads();
    if (t == 0) {
        const float* Woi = Wo + (size_t)i * 32;
        float v = bo[i];
        #pragma unroll
        for (int j = 0; j < 32; ++j) v = fmaf(sH2[j], Woi[j], v);
        out[b] = v + sPsq;
    }
}

extern "C" void kernel_launch(void* const* d_in, const int* in_sizes, int n_in,
                              void* d_out, int out_size, void* d_ws, size_t ws_size,
                              hipStream_t stream) {
    const float* us_p  = (const float*)d_in[0];
    const float* them  = (const float*)d_in[1];
    const int*   widx  = (const int*)d_in[2];
    const float* wval  = (const float*)d_in[3];
    const int*   bidx  = (const int*)d_in[4];
    const float* bval  = (const float*)d_in[5];
    const int*   pidx  = (const int*)d_in[6];
    const int*   lidx  = (const int*)d_in[7];
    const float* ftw   = (const float*)d_in[8];
    const float* ftb   = (const float*)d_in[9];
    const float* lsqs  = (const float*)d_in[10];
    const float* W1    = (const float*)d_in[11];
    const float* b1    = (const float*)d_in[12];
    const float* W2    = (const float*)d_in[13];
    const float* b2    = (const float*)d_in[14];
    const float* Wo    = (const float*)d_in[15];
    const float* bo    = (const float*)d_in[16];
    float* out = (float*)d_out;

    if (ws_size >= WS_NEEDED) {
        unsigned short* tblbf = (unsigned short*)d_ws;
        unsigned short* w1bf  = (unsigned short*)((char*)d_ws + W1_OFF);
        conv_bf16<<<dim3(8192), dim3(256), 0, stream>>>(ftw, tblbf, (int)(TBL_ELEMS / 4));
        conv_bf16<<<dim3(256),  dim3(256), 0, stream>>>(W1,  w1bf,  (int)(W1_ELEMS / 4));
        nnue_fwd_bf16<<<dim3(BB), dim3(NT), 0, stream>>>(
            us_p, them, widx, wval, bidx, bval, pidx, lidx,
            tblbf, ftb, lsqs, w1bf, b1, W2, b2, Wo, bo, out);
    } else {
        nnue_fwd_f32<<<dim3(BB), dim3(NT), 0, stream>>>(
            us_p, them, widx, wval, bidx, bval, pidx, lidx,
            ftw, ftb, lsqs, W1, b1, W2, b2, Wo, bo, out);
    }
}